// Round 9
// baseline (399.608 us; speedup 1.0000x reference)
//
#include <hip/hip_runtime.h>

#define NG 20000
#define BOFF 12800000u   // flat-index offset of batch b+32: 32*K*N

// ---------- JAX threefry2x32, key = (0, 42) ----------
__device__ __forceinline__ void threefry2x32(unsigned x0, unsigned x1,
                                             unsigned& o0, unsigned& o1) {
  const unsigned ks0 = 0u;
  const unsigned ks1 = 42u;
  const unsigned ks2 = 0x1BD11BDAu ^ 0u ^ 42u;
  x0 += ks0; x1 += ks1;
#define TFR(r) { x0 += x1; x1 = (x1 << (r)) | (x1 >> (32 - (r))); x1 ^= x0; }
  TFR(13) TFR(15) TFR(26) TFR(6)
  x0 += ks1; x1 += ks2 + 1u;
  TFR(17) TFR(29) TFR(16) TFR(24)
  x0 += ks2; x1 += ks0 + 2u;
  TFR(13) TFR(15) TFR(26) TFR(6)
  x0 += ks0; x1 += ks1 + 3u;
  TFR(17) TFR(29) TFR(16) TFR(24)
  x0 += ks1; x1 += ks2 + 4u;
  TFR(13) TFR(15) TFR(26) TFR(6)
  x0 += ks2; x1 += ks0 + 5u;
#undef TFR
  o0 = x0; o1 = x1;
}

// JAX threefry_partitionable: bits(i) = o0 ^ o1 of threefry((0,42),(0,i))
__device__ __forceinline__ unsigned tfbits(unsigned ctr) {
  unsigned o0, o1;
  threefry2x32(0u, ctr, o0, o1);
  return o0 ^ o1;
}

// fp32 fast-screen gumbel (hw log path); abs err vs fp64 < ~1e-5
__device__ __forceinline__ float gumbel32(unsigned bits) {
  float f = __uint_as_float((bits >> 9) | 0x3f800000u) - 1.0f;
  float u = fmaxf(f, 1.17549435e-38f);
  return -__logf(-__logf(u));
}

// exact fp64 gumbel; u is a 23-bit dyadic rational, exact in double
__device__ __forceinline__ double gumbel64(unsigned bits) {
  float f = __uint_as_float((bits >> 9) | 0x3f800000u) - 1.0f;
  double u = (double)fmaxf(f, 1.17549435e-38f);
  return -log(-log(u));
}

// pack fp64 score (top 49 monotone bits) + 15-bit (32767-n): u64 max == (score, then smaller n)
__device__ __forceinline__ unsigned long long packcell(double v, int n) {
  unsigned long long u = (unsigned long long)__double_as_longlong(v);
  u = (u >> 63) ? ~u : (u | 0x8000000000000000ull);
  return (u & 0xFFFFFFFFFFFF8000ull) | (unsigned long long)(32767 - n);
}

// ---------- prep: Wf=Wk@W1k (fp64), Q, qbT; c12 table; zero cells ----------
__global__ __launch_bounds__(128) void kprep(
    const float* __restrict__ pe, const float* __restrict__ Wq,
    const float* __restrict__ bq, const float* __restrict__ Wk,
    const float* __restrict__ bk, const float* __restrict__ W1,
    const float* __restrict__ b1, const float* __restrict__ w2,
    double* __restrict__ Wfd, double* __restrict__ qbT,
    float* __restrict__ Qm, unsigned long long* __restrict__ cells,
    double2* __restrict__ c12) {
  __shared__ float L[512];
  __shared__ double Ld[128];
  const int t = threadIdx.x;
  const int bid = blockIdx.x;
  if (bid < 256) {
    L[t] = Wk[bid * 128 + t];
    __syncthreads();
    double acc = 0.0;
    #pragma unroll 8
    for (int j = 0; j < 128; ++j)
      acc = fma((double)L[j], (double)W1[(128 + j) * 128 + t], acc);
    Wfd[bid * 128 + t] = acc;
  } else if (bid < 320) {
    const int b = bid - 256;
    #pragma unroll
    for (int i = 0; i < 4; ++i) L[t + 128 * i] = pe[b * 512 + t + 128 * i];
    __syncthreads();
    double q = (double)bq[t];
    #pragma unroll 4
    for (int f = 0; f < 512; ++f)
      q = fma((double)L[f], (double)Wq[f * 128 + t], q);
    Qm[b * 128 + t] = (float)q;   // epilogue path stays fp32
    Ld[t] = q;
    __syncthreads();
    // qb[b,d=t] = Q@W1[:128] + b1 + bk@W1[128:]; store transposed qbT[d][b]
    double acc = (double)b1[t];
    #pragma unroll 4
    for (int j = 0; j < 128; ++j) {
      acc = fma(Ld[j], (double)W1[j * 128 + t], acc);
      acc = fma((double)bk[j], (double)W1[(128 + j) * 128 + t], acc);
    }
    qbT[t * 64 + b] = acc;
  } else {
    for (int i = t; i < 1280; i += 128) cells[i] = 0ull;
    const double w2d = (double)w2[t];
    c12[t] = make_double2(0.55 * w2d, 0.45 * w2d);
  }
}

// ---------- fused kp+sim: dbuf LDS Wfd chunks (f=16), conflict-free staging ----------
// block = 256 threads, 16 genes. Phase 1: thread (d=t&127, h=t>>7) accumulates
// kp[d][g] for genes h*8..h*8+7. Phase 2: kp->LDS; wave wv computes sim for
// genes {wv, wv+4, wv+8, wv+12}, lane = batch. FMA order identical to R8.
__global__ __launch_bounds__(256, 4) void kfused(
    const float* __restrict__ ge, const double* __restrict__ Wfd,
    const double* __restrict__ qbT, const double2* __restrict__ c12,
    double* __restrict__ simd, float* __restrict__ sim2f) {
  __shared__ double W0[2048];   // chunk buffer / kpL[16][128]
  __shared__ double W1[2048];   // chunk buffer / simL[64][17]
  const int t = threadIdx.x;
  const int d = t & 127;
  const int h = t >> 7;
  const int wv = t >> 6;
  const int lane = t & 63;
  const int g0 = blockIdx.x * 16;     // 1250 blocks * 16 genes

  double acc[8];
  #pragma unroll
  for (int g = 0; g < 8; ++g) acc[g] = 0.0;
  const float* gbase = ge + (size_t)(g0 + h * 8) * 256;

  // preload chunk 0: thread t -> doubles [i*512 + 2t] (global coalesced 16B/lane,
  // LDS store lane-contiguous -> conflict-free)
  #pragma unroll
  for (int i = 0; i < 4; ++i)
    *(double2*)(W0 + i * 512 + 2 * t) = *(const double2*)(Wfd + i * 512 + 2 * t);
  __syncthreads();

  for (int c = 0; c < 16; ++c) {
    double* buf = (c & 1) ? W1 : W0;
    double* nbuf = (c & 1) ? W0 : W1;
    double2 nx[4];
    if (c < 15) {
      const double* src = Wfd + (c + 1) * 2048 + 2 * t;
      #pragma unroll
      for (int i = 0; i < 4; ++i) nx[i] = *(const double2*)(src + i * 512);
    }
    #pragma unroll
    for (int fl = 0; fl < 16; fl += 4) {
      float4 av[8];                   // wave-uniform -> s_load_dwordx4
      #pragma unroll
      for (int g = 0; g < 8; ++g)
        av[g] = *(const float4*)(gbase + g * 256 + c * 16 + fl);
      #pragma unroll
      for (int j = 0; j < 4; ++j) {
        const double wj = buf[(fl + j) * 128 + d];
        acc[0] = fma((double)(&av[0].x)[j], wj, acc[0]);
        acc[1] = fma((double)(&av[1].x)[j], wj, acc[1]);
        acc[2] = fma((double)(&av[2].x)[j], wj, acc[2]);
        acc[3] = fma((double)(&av[3].x)[j], wj, acc[3]);
        acc[4] = fma((double)(&av[4].x)[j], wj, acc[4]);
        acc[5] = fma((double)(&av[5].x)[j], wj, acc[5]);
        acc[6] = fma((double)(&av[6].x)[j], wj, acc[6]);
        acc[7] = fma((double)(&av[7].x)[j], wj, acc[7]);
      }
    }
    if (c < 15) {
      #pragma unroll
      for (int i = 0; i < 4; ++i)
        *(double2*)(nbuf + i * 512 + 2 * t) = nx[i];
    }
    __syncthreads();
  }

  // ---- phase 2: kp -> W0 (kpL[g][d]), sim -> W1 (simL) ----
  #pragma unroll
  for (int g = 0; g < 8; ++g) W0[(h * 8 + g) * 128 + d] = acc[g];
  __syncthreads();

  double s[4];
  #pragma unroll
  for (int j = 0; j < 4; ++j) s[j] = 0.0;
  for (int dd = 0; dd < 128; ++dd) {
    const double2 cc = c12[dd];                   // uniform -> s_load
    const double qv = qbT[dd * 64 + lane];        // coalesced, L1-hot
    #pragma unroll
    for (int j = 0; j < 4; ++j) {
      const double kv = W0[(wv + j * 4) * 128 + dd];  // wave-uniform broadcast
      const double tt = qv + kv;
      s[j] = fma(tt, cc.x, s[j]);
      s[j] = fma(fabs(tt), cc.y, s[j]);
    }
  }
  #pragma unroll
  for (int j = 0; j < 4; ++j) W1[lane * 17 + (wv + j * 4)] = s[j];
  __syncthreads();

  // write-out: thread -> (b = t>>2, quarter j2 = t&3): 4 doubles + 4 floats
  {
    const int b = t >> 2, j2 = t & 3;
    const double v0 = W1[b * 17 + j2 * 4 + 0];
    const double v1 = W1[b * 17 + j2 * 4 + 1];
    const double v2 = W1[b * 17 + j2 * 4 + 2];
    const double v3 = W1[b * 17 + j2 * 4 + 3];
    double* dst = simd + (size_t)b * NG + g0 + j2 * 4;
    *(double2*)dst = make_double2(v0, v1);
    *(double2*)(dst + 2) = make_double2(v2, v3);
    float4 f4;
    f4.x = (float)(2.0 * v0); f4.y = (float)(2.0 * v1);
    f4.z = (float)(2.0 * v2); f4.w = (float)(2.0 * v3);
    *(float4*)(sim2f + (size_t)b * NG + g0 + j2 * 4) = f4;
  }
}

// ---------- selection: single-pass fp32 top-2 screen (sim2f), fp64 exact at end ----------
__global__ __launch_bounds__(256) void ksel2(
    const double* __restrict__ simd, const float* __restrict__ sim2f,
    unsigned long long* __restrict__ cells) {
  const int t = threadIdx.x;
  const int wv = t >> 6;
  const int lane = t & 63;
  const int p = (int)(blockIdx.x & 7) * 4 + wv;   // pair 0..31
  const int c = (int)(blockIdx.x >> 3);           // chunk 0..246
  const int n0 = c * 81;
  const int nEnd = min(n0 + 81, NG);
  const int k = lane % 20;
  const int gi = lane / 20;
  const bool active = lane < 60;
  const double* sdA = simd + (size_t)p * NG;
  const double* sdB = simd + (size_t)(p + 32) * NG;
  const float* seA = sim2f + (size_t)p * NG;
  const float* seB = sim2f + (size_t)(p + 32) * NG;
  const unsigned kbase = (unsigned)(p * 20 + k) * (unsigned)NG;

  float m1A = -3e38f, m2A = -3e38f, m1B = -3e38f, m2B = -3e38f;
  int n1A = -1, n2A = -1, n1B = -1, n2B = -1;
  unsigned c1A = 0, c2A = 0, c1B = 0, c2B = 0;

  for (int it = 0; it < 27; ++it) {
    const int n = n0 + it * 3 + gi;
    const bool v = active && (n < nEnd);
    const int nc = v ? n : n0;
    const unsigned idxA = kbase + (unsigned)nc;
    const unsigned bA = tfbits(idxA);
    const unsigned bB = tfbits(idxA + BOFF);
    const float s2A = v ? seA[nc] : -3e38f;
    const float s2B = v ? seB[nc] : -3e38f;
    const float sA = s2A + gumbel32(bA);
    const float sB = s2B + gumbel32(bB);
    if (sA > m1A) { m2A = m1A; n2A = n1A; c2A = c1A; m1A = sA; n1A = n; c1A = bA; }
    else if (sA > m2A) { m2A = sA; n2A = n; c2A = bA; }
    if (sB > m1B) { m2B = m1B; n2B = n1B; c2B = c1B; m1B = sB; n1B = n; c1B = bB; }
    else if (sB > m2B) { m2B = sB; n2B = n; c2B = bB; }
  }

  // exact fp64 for the fp32 winner (+ runner-up iff ambiguous: gap < 1e-4 >> 1e-5 screen err)
  unsigned long long pbA = 0ull, pbB = 0ull;
  if (n1A >= 0) {
    pbA = packcell(2.0 * sdA[n1A] + gumbel64(c1A), n1A);
    if (n2A >= 0 && (m1A - m2A) < 1e-4f) {
      const unsigned long long u2 = packcell(2.0 * sdA[n2A] + gumbel64(c2A), n2A);
      if (u2 > pbA) pbA = u2;
    }
  }
  if (n1B >= 0) {
    pbB = packcell(2.0 * sdB[n1B] + gumbel64(c1B), n1B);
    if (n2B >= 0 && (m1B - m2B) < 1e-4f) {
      const unsigned long long u2 = packcell(2.0 * sdB[n2B] + gumbel64(c2B), n2B);
      if (u2 > pbB) pbB = u2;
    }
  }

  // fold gi slots (lanes +20, +40), then one atomic per (batch, k)
  #pragma unroll
  for (int sh = 20; sh <= 40; sh += 20) {
    const unsigned long long oA = __shfl(pbA, lane + sh, 64);
    const unsigned long long oB = __shfl(pbB, lane + sh, 64);
    if (lane < 20) {
      if (oA > pbA) pbA = oA;
      if (oB > pbB) pbB = oB;
    }
  }
  if (lane < 20 && pbA) atomicMax(&cells[p * 20 + lane], pbA);
  if (lane < 20 && pbB) atomicMax(&cells[(p + 32) * 20 + lane], pbB);
}

// ---------- epilogue V: one BLOCK per (b,k); f-range split across 4 waves ----------
__global__ __launch_bounds__(256) void kfinalV(
    const float* __restrict__ ge, const float* __restrict__ Wv,
    const float* __restrict__ bv, const float* __restrict__ Qm,
    const unsigned long long* __restrict__ cells,
    float* __restrict__ Vws, float* __restrict__ scws) {
  __shared__ float VP[4][128];
  __shared__ float Vf[128];
  const int t = threadIdx.x;
  const int wv = t >> 6;
  const int lane = t & 63;
  const int task = blockIdx.x;            // 1280 tasks = (b,k)
  const int b = task / 20;
  const unsigned long long cell = cells[task];
  const int n = 32767 - (int)(cell & 0x7FFFull);
  const float* gr = ge + (size_t)n * 256;
  float vx = 0.f, vy = 0.f;
  const int f0 = wv * 64;
  #pragma unroll
  for (int f = 0; f < 64; f += 4) {
    const float4 gv = *(const float4*)(gr + f0 + f);   // wave-uniform -> s_load
    const float2 w0 = ((const float2*)(Wv + (size_t)(f0 + f + 0) * 128))[lane];
    const float2 w1 = ((const float2*)(Wv + (size_t)(f0 + f + 1) * 128))[lane];
    const float2 w2_ = ((const float2*)(Wv + (size_t)(f0 + f + 2) * 128))[lane];
    const float2 w3 = ((const float2*)(Wv + (size_t)(f0 + f + 3) * 128))[lane];
    vx = fmaf(gv.x, w0.x, vx); vy = fmaf(gv.x, w0.y, vy);
    vx = fmaf(gv.y, w1.x, vx); vy = fmaf(gv.y, w1.y, vy);
    vx = fmaf(gv.z, w2_.x, vx); vy = fmaf(gv.z, w2_.y, vy);
    vx = fmaf(gv.w, w3.x, vx); vy = fmaf(gv.w, w3.y, vy);
  }
  VP[wv][2 * lane] = vx;
  VP[wv][2 * lane + 1] = vy;
  __syncthreads();
  if (t < 128) {
    const float v = bv[t] + (VP[0][t] + VP[1][t]) + (VP[2][t] + VP[3][t]);
    Vf[t] = v;
    Vws[(size_t)task * 128 + t] = v;
  }
  __syncthreads();
  if (wv == 0) {
    const float2 vv = *(const float2*)(Vf + 2 * lane);
    const float2 qv = ((const float2*)(Qm + b * 128))[lane];
    float pr = qv.x * vv.x + qv.y * vv.y;
    #pragma unroll
    for (int off = 32; off; off >>= 1) pr += __shfl_xor(pr, off, 64);
    if (lane == 0) scws[task] = pr * 0.08838834764831845f;  // 1/sqrt(128)
  }
}

// ---------- epilogue C: softmax over K=20, weighted context sum ----------
__global__ __launch_bounds__(128) void kfinalC(
    const float* __restrict__ Vws, const float* __restrict__ scws,
    float* __restrict__ out) {
  const int b = blockIdx.x;
  const int t = threadIdx.x;   // t = d
  float sc[20];
  float m = -3.0e38f;
  #pragma unroll
  for (int i = 0; i < 20; ++i) { sc[i] = scws[b * 20 + i]; m = fmaxf(m, sc[i]); }
  float s = 0.f;
  #pragma unroll
  for (int i = 0; i < 20; ++i) { sc[i] = expf(sc[i] - m); s += sc[i]; }
  const float inv = 1.0f / s;
  float acc = 0.f;
  #pragma unroll 4
  for (int i = 0; i < 20; ++i)
    acc = fmaf(sc[i] * inv, Vws[(size_t)(b * 20 + i) * 128 + t], acc);
  out[b * 128 + t] = acc;
}

extern "C" void kernel_launch(void* const* d_in, const int* in_sizes, int n_in,
                              void* d_out, int out_size, void* d_ws, size_t ws_size,
                              hipStream_t stream) {
  (void)in_sizes; (void)n_in; (void)out_size; (void)ws_size;
  const float* pe = (const float*)d_in[0];
  const float* ge = (const float*)d_in[1];
  const float* Wq = (const float*)d_in[2];
  const float* bq = (const float*)d_in[3];
  const float* Wk = (const float*)d_in[4];
  const float* bk = (const float*)d_in[5];
  const float* Wv = (const float*)d_in[6];
  const float* bvp = (const float*)d_in[7];
  const float* W1 = (const float*)d_in[8];
  const float* b1 = (const float*)d_in[9];
  const float* w2 = (const float*)d_in[10];
  // d_in[11] = b2: uniform over n -> cancels in argmax; absent from output path.

  char* w = (char*)d_ws;
  double* Wfd = (double*)w;                              // 262144 B
  double* qbT = (double*)(w + 262144);                   // 65536 B
  float* Qm = (float*)(w + 327680);                      // 32768 B
  unsigned long long* cells =
      (unsigned long long*)(w + 360448);                 // 10240 B
  double2* c12 = (double2*)(w + 370688);                 // 2048 B
  double* simd = (double*)(w + 372736);                  // 10,240,000 B
  float* sim2f = (float*)(w + 10612736);                 // 5,120,000 B
  float* Vws = (float*)(w + 15732736);                   // 655,360 B
  float* scws = (float*)(w + 16388096);                  // 5,120 B (~16.4 MB total)
  float* out = (float*)d_out;

  kprep<<<dim3(321), dim3(128), 0, stream>>>(pe, Wq, bq, Wk, bk, W1, b1, w2,
                                             Wfd, qbT, Qm, cells, c12);
  kfused<<<dim3(1250), dim3(256), 0, stream>>>(ge, Wfd, qbT, c12, simd, sim2f);
  ksel2<<<dim3(1976), dim3(256), 0, stream>>>(simd, sim2f, cells);
  kfinalV<<<dim3(1280), dim3(256), 0, stream>>>(ge, Wv, bvp, Qm, cells, Vws, scws);
  kfinalC<<<dim3(64), dim3(128), 0, stream>>>(Vws, scws, out);
}

// Round 10
// 362.615 us; speedup vs baseline: 1.1020x; 1.1020x over previous
//
#include <hip/hip_runtime.h>

#define NG 20000
#define BOFF 12800000u   // flat-index offset of batch b+32: 32*K*N

// ---------- JAX threefry2x32, key = (0, 42) ----------
__device__ __forceinline__ void threefry2x32(unsigned x0, unsigned x1,
                                             unsigned& o0, unsigned& o1) {
  const unsigned ks0 = 0u;
  const unsigned ks1 = 42u;
  const unsigned ks2 = 0x1BD11BDAu ^ 0u ^ 42u;
  x0 += ks0; x1 += ks1;
#define TFR(r) { x0 += x1; x1 = (x1 << (r)) | (x1 >> (32 - (r))); x1 ^= x0; }
  TFR(13) TFR(15) TFR(26) TFR(6)
  x0 += ks1; x1 += ks2 + 1u;
  TFR(17) TFR(29) TFR(16) TFR(24)
  x0 += ks2; x1 += ks0 + 2u;
  TFR(13) TFR(15) TFR(26) TFR(6)
  x0 += ks0; x1 += ks1 + 3u;
  TFR(17) TFR(29) TFR(16) TFR(24)
  x0 += ks1; x1 += ks2 + 4u;
  TFR(13) TFR(15) TFR(26) TFR(6)
  x0 += ks2; x1 += ks0 + 5u;
#undef TFR
  o0 = x0; o1 = x1;
}

// JAX threefry_partitionable: bits(i) = o0 ^ o1 of threefry((0,42),(0,i))
__device__ __forceinline__ unsigned tfbits(unsigned ctr) {
  unsigned o0, o1;
  threefry2x32(0u, ctr, o0, o1);
  return o0 ^ o1;
}

// fp32 fast-screen gumbel (hw log path); abs err vs fp64 < ~1e-5
__device__ __forceinline__ float gumbel32(unsigned bits) {
  float f = __uint_as_float((bits >> 9) | 0x3f800000u) - 1.0f;
  float u = fmaxf(f, 1.17549435e-38f);
  return -__logf(-__logf(u));
}

// exact fp64 gumbel; u is a 23-bit dyadic rational, exact in double
__device__ __forceinline__ double gumbel64(unsigned bits) {
  float f = __uint_as_float((bits >> 9) | 0x3f800000u) - 1.0f;
  double u = (double)fmaxf(f, 1.17549435e-38f);
  return -log(-log(u));
}

// pack fp64 score (top 49 monotone bits) + 15-bit (32767-n): u64 max == (score, then smaller n)
__device__ __forceinline__ unsigned long long packcell(double v, int n) {
  unsigned long long u = (unsigned long long)__double_as_longlong(v);
  u = (u >> 63) ? ~u : (u | 0x8000000000000000ull);
  return (u & 0xFFFFFFFFFFFF8000ull) | (unsigned long long)(32767 - n);
}

// ---------- prep: Wf=Wk@W1k (fp64), Q, qbT; c12 table; zero cells ----------
__global__ __launch_bounds__(128) void kprep(
    const float* __restrict__ pe, const float* __restrict__ Wq,
    const float* __restrict__ bq, const float* __restrict__ Wk,
    const float* __restrict__ bk, const float* __restrict__ W1,
    const float* __restrict__ b1, const float* __restrict__ w2,
    double* __restrict__ Wfd, double* __restrict__ qbT,
    float* __restrict__ Qm, unsigned long long* __restrict__ cells,
    double2* __restrict__ c12) {
  __shared__ float L[512];
  __shared__ double Ld[128];
  const int t = threadIdx.x;
  const int bid = blockIdx.x;
  if (bid < 256) {
    L[t] = Wk[bid * 128 + t];
    __syncthreads();
    double acc = 0.0;
    #pragma unroll 8
    for (int j = 0; j < 128; ++j)
      acc = fma((double)L[j], (double)W1[(128 + j) * 128 + t], acc);
    Wfd[bid * 128 + t] = acc;
  } else if (bid < 320) {
    const int b = bid - 256;
    #pragma unroll
    for (int i = 0; i < 4; ++i) L[t + 128 * i] = pe[b * 512 + t + 128 * i];
    __syncthreads();
    double q = (double)bq[t];
    #pragma unroll 4
    for (int f = 0; f < 512; ++f)
      q = fma((double)L[f], (double)Wq[f * 128 + t], q);
    Qm[b * 128 + t] = (float)q;   // epilogue path stays fp32
    Ld[t] = q;
    __syncthreads();
    // qb[b,d=t] = Q@W1[:128] + b1 + bk@W1[128:]; store transposed qbT[d][b]
    double acc = (double)b1[t];
    #pragma unroll 4
    for (int j = 0; j < 128; ++j) {
      acc = fma(Ld[j], (double)W1[j * 128 + t], acc);
      acc = fma((double)bk[j], (double)W1[(128 + j) * 128 + t], acc);
    }
    qbT[t * 64 + b] = acc;
  } else {
    for (int i = t; i < 1280; i += 128) cells[i] = 0ull;
    const double w2d = (double)w2[t];
    c12[t] = make_double2(0.55 * w2d, 0.45 * w2d);
  }
}

// ---------- fused kp+sim: barrier-free phase 1, 8-deep register pipeline ----------
// block = 256 threads, 16 genes. Phase 1: thread (d=t&127, h=t>>7) accumulates
// kp[d][g] for genes h*8..h*8+7; Wfd column streamed via 8-deep double prefetch
// (L2-resident), gene rows via wave-uniform s_loads. Phase 2: kp->LDS; wave wv
// computes sim for genes {wv, wv+4, wv+8, wv+12}, lane = batch. Per-acc f-order
// ascending -> bit-identical to R7/R8/R9.
__global__ __launch_bounds__(256) void kfused(
    const float* __restrict__ ge, const double* __restrict__ Wfd,
    const double* __restrict__ qbT, const double2* __restrict__ c12,
    double* __restrict__ simd, float* __restrict__ sim2f) {
  __shared__ double W0[2048];   // kpL[16][128]
  __shared__ double W1[1088];   // simL[64][17]
  const int t = threadIdx.x;
  const int d = t & 127;
  const int h = t >> 7;
  const int wv = t >> 6;
  const int lane = t & 63;
  const int g0 = blockIdx.x * 16;     // 1250 blocks * 16 genes

  double acc[8];
  #pragma unroll
  for (int g = 0; g < 8; ++g) acc[g] = 0.0;
  const float* gbase = ge + (size_t)(g0 + h * 8) * 256;
  const double* wbase = Wfd + d;

  double wc[8], wn[8];
  #pragma unroll
  for (int j = 0; j < 8; ++j) wc[j] = wbase[j * 128];

  for (int f0 = 0; f0 < 256; f0 += 8) {
    if (f0 < 248) {
      #pragma unroll
      for (int j = 0; j < 8; ++j) wn[j] = wbase[(f0 + 8 + j) * 128];
    }
    float4 av0[8], av1[8];            // wave-uniform -> s_load_dwordx4
    #pragma unroll
    for (int g = 0; g < 8; ++g) {
      av0[g] = *(const float4*)(gbase + g * 256 + f0);
      av1[g] = *(const float4*)(gbase + g * 256 + f0 + 4);
    }
    #pragma unroll
    for (int j = 0; j < 4; ++j) {
      const double wj = wc[j];
      acc[0] = fma((double)(&av0[0].x)[j], wj, acc[0]);
      acc[1] = fma((double)(&av0[1].x)[j], wj, acc[1]);
      acc[2] = fma((double)(&av0[2].x)[j], wj, acc[2]);
      acc[3] = fma((double)(&av0[3].x)[j], wj, acc[3]);
      acc[4] = fma((double)(&av0[4].x)[j], wj, acc[4]);
      acc[5] = fma((double)(&av0[5].x)[j], wj, acc[5]);
      acc[6] = fma((double)(&av0[6].x)[j], wj, acc[6]);
      acc[7] = fma((double)(&av0[7].x)[j], wj, acc[7]);
    }
    #pragma unroll
    for (int j = 0; j < 4; ++j) {
      const double wj = wc[4 + j];
      acc[0] = fma((double)(&av1[0].x)[j], wj, acc[0]);
      acc[1] = fma((double)(&av1[1].x)[j], wj, acc[1]);
      acc[2] = fma((double)(&av1[2].x)[j], wj, acc[2]);
      acc[3] = fma((double)(&av1[3].x)[j], wj, acc[3]);
      acc[4] = fma((double)(&av1[4].x)[j], wj, acc[4]);
      acc[5] = fma((double)(&av1[5].x)[j], wj, acc[5]);
      acc[6] = fma((double)(&av1[6].x)[j], wj, acc[6]);
      acc[7] = fma((double)(&av1[7].x)[j], wj, acc[7]);
    }
    #pragma unroll
    for (int j = 0; j < 8; ++j) wc[j] = wn[j];
  }

  // ---- phase 2: kp -> W0 (kpL[g][d]), then sim (4 genes/wave, lane = batch) ----
  #pragma unroll
  for (int g = 0; g < 8; ++g) W0[(h * 8 + g) * 128 + d] = acc[g];
  __syncthreads();

  double s[4];
  #pragma unroll
  for (int j = 0; j < 4; ++j) s[j] = 0.0;
  for (int dd = 0; dd < 128; ++dd) {
    const double2 cc = c12[dd];                   // uniform -> s_load
    const double qv = qbT[dd * 64 + lane];        // coalesced, L1-hot
    #pragma unroll
    for (int j = 0; j < 4; ++j) {
      const double kv = W0[(wv + j * 4) * 128 + dd];  // wave-uniform broadcast
      const double tt = qv + kv;
      s[j] = fma(tt, cc.x, s[j]);
      s[j] = fma(fabs(tt), cc.y, s[j]);
    }
  }
  #pragma unroll
  for (int j = 0; j < 4; ++j) W1[lane * 17 + (wv + j * 4)] = s[j];
  __syncthreads();

  // write-out: thread -> (b = t>>2, quarter j2 = t&3): 4 doubles + 4 floats
  {
    const int b = t >> 2, j2 = t & 3;
    const double v0 = W1[b * 17 + j2 * 4 + 0];
    const double v1 = W1[b * 17 + j2 * 4 + 1];
    const double v2 = W1[b * 17 + j2 * 4 + 2];
    const double v3 = W1[b * 17 + j2 * 4 + 3];
    double* dst = simd + (size_t)b * NG + g0 + j2 * 4;
    *(double2*)dst = make_double2(v0, v1);
    *(double2*)(dst + 2) = make_double2(v2, v3);
    float4 f4;
    f4.x = (float)(2.0 * v0); f4.y = (float)(2.0 * v1);
    f4.z = (float)(2.0 * v2); f4.w = (float)(2.0 * v3);
    *(float4*)(sim2f + (size_t)b * NG + g0 + j2 * 4) = f4;
  }
}

// ---------- selection: single-pass fp32 top-2 screen (sim2f), fp64 exact at end ----------
__global__ __launch_bounds__(256) void ksel2(
    const double* __restrict__ simd, const float* __restrict__ sim2f,
    unsigned long long* __restrict__ cells) {
  const int t = threadIdx.x;
  const int wv = t >> 6;
  const int lane = t & 63;
  const int p = (int)(blockIdx.x & 7) * 4 + wv;   // pair 0..31
  const int c = (int)(blockIdx.x >> 3);           // chunk 0..246
  const int n0 = c * 81;
  const int nEnd = min(n0 + 81, NG);
  const int k = lane % 20;
  const int gi = lane / 20;
  const bool active = lane < 60;
  const double* sdA = simd + (size_t)p * NG;
  const double* sdB = simd + (size_t)(p + 32) * NG;
  const float* seA = sim2f + (size_t)p * NG;
  const float* seB = sim2f + (size_t)(p + 32) * NG;
  const unsigned kbase = (unsigned)(p * 20 + k) * (unsigned)NG;

  float m1A = -3e38f, m2A = -3e38f, m1B = -3e38f, m2B = -3e38f;
  int n1A = -1, n2A = -1, n1B = -1, n2B = -1;
  unsigned c1A = 0, c2A = 0, c1B = 0, c2B = 0;

  for (int it = 0; it < 27; ++it) {
    const int n = n0 + it * 3 + gi;
    const bool v = active && (n < nEnd);
    const int nc = v ? n : n0;
    const unsigned idxA = kbase + (unsigned)nc;
    const unsigned bA = tfbits(idxA);
    const unsigned bB = tfbits(idxA + BOFF);
    const float s2A = v ? seA[nc] : -3e38f;
    const float s2B = v ? seB[nc] : -3e38f;
    const float sA = s2A + gumbel32(bA);
    const float sB = s2B + gumbel32(bB);
    if (sA > m1A) { m2A = m1A; n2A = n1A; c2A = c1A; m1A = sA; n1A = n; c1A = bA; }
    else if (sA > m2A) { m2A = sA; n2A = n; c2A = bA; }
    if (sB > m1B) { m2B = m1B; n2B = n1B; c2B = c1B; m1B = sB; n1B = n; c1B = bB; }
    else if (sB > m2B) { m2B = sB; n2B = n; c2B = bB; }
  }

  // exact fp64 for the fp32 winner (+ runner-up iff ambiguous: gap < 1e-4 >> 1e-5 screen err)
  unsigned long long pbA = 0ull, pbB = 0ull;
  if (n1A >= 0) {
    pbA = packcell(2.0 * sdA[n1A] + gumbel64(c1A), n1A);
    if (n2A >= 0 && (m1A - m2A) < 1e-4f) {
      const unsigned long long u2 = packcell(2.0 * sdA[n2A] + gumbel64(c2A), n2A);
      if (u2 > pbA) pbA = u2;
    }
  }
  if (n1B >= 0) {
    pbB = packcell(2.0 * sdB[n1B] + gumbel64(c1B), n1B);
    if (n2B >= 0 && (m1B - m2B) < 1e-4f) {
      const unsigned long long u2 = packcell(2.0 * sdB[n2B] + gumbel64(c2B), n2B);
      if (u2 > pbB) pbB = u2;
    }
  }

  // fold gi slots (lanes +20, +40), then one atomic per (batch, k)
  #pragma unroll
  for (int sh = 20; sh <= 40; sh += 20) {
    const unsigned long long oA = __shfl(pbA, lane + sh, 64);
    const unsigned long long oB = __shfl(pbB, lane + sh, 64);
    if (lane < 20) {
      if (oA > pbA) pbA = oA;
      if (oB > pbB) pbB = oB;
    }
  }
  if (lane < 20 && pbA) atomicMax(&cells[p * 20 + lane], pbA);
  if (lane < 20 && pbB) atomicMax(&cells[(p + 32) * 20 + lane], pbB);
}

// ---------- epilogue V: one BLOCK per (b,k); f-range split across 4 waves ----------
__global__ __launch_bounds__(256) void kfinalV(
    const float* __restrict__ ge, const float* __restrict__ Wv,
    const float* __restrict__ bv, const float* __restrict__ Qm,
    const unsigned long long* __restrict__ cells,
    float* __restrict__ Vws, float* __restrict__ scws) {
  __shared__ float VP[4][128];
  __shared__ float Vf[128];
  const int t = threadIdx.x;
  const int wv = t >> 6;
  const int lane = t & 63;
  const int task = blockIdx.x;            // 1280 tasks = (b,k)
  const int b = task / 20;
  const unsigned long long cell = cells[task];
  const int n = 32767 - (int)(cell & 0x7FFFull);
  const float* gr = ge + (size_t)n * 256;
  float vx = 0.f, vy = 0.f;
  const int f0 = wv * 64;
  #pragma unroll
  for (int f = 0; f < 64; f += 4) {
    const float4 gv = *(const float4*)(gr + f0 + f);   // wave-uniform -> s_load
    const float2 w0 = ((const float2*)(Wv + (size_t)(f0 + f + 0) * 128))[lane];
    const float2 w1 = ((const float2*)(Wv + (size_t)(f0 + f + 1) * 128))[lane];
    const float2 w2_ = ((const float2*)(Wv + (size_t)(f0 + f + 2) * 128))[lane];
    const float2 w3 = ((const float2*)(Wv + (size_t)(f0 + f + 3) * 128))[lane];
    vx = fmaf(gv.x, w0.x, vx); vy = fmaf(gv.x, w0.y, vy);
    vx = fmaf(gv.y, w1.x, vx); vy = fmaf(gv.y, w1.y, vy);
    vx = fmaf(gv.z, w2_.x, vx); vy = fmaf(gv.z, w2_.y, vy);
    vx = fmaf(gv.w, w3.x, vx); vy = fmaf(gv.w, w3.y, vy);
  }
  VP[wv][2 * lane] = vx;
  VP[wv][2 * lane + 1] = vy;
  __syncthreads();
  if (t < 128) {
    const float v = bv[t] + (VP[0][t] + VP[1][t]) + (VP[2][t] + VP[3][t]);
    Vf[t] = v;
    Vws[(size_t)task * 128 + t] = v;
  }
  __syncthreads();
  if (wv == 0) {
    const float2 vv = *(const float2*)(Vf + 2 * lane);
    const float2 qv = ((const float2*)(Qm + b * 128))[lane];
    float pr = qv.x * vv.x + qv.y * vv.y;
    #pragma unroll
    for (int off = 32; off; off >>= 1) pr += __shfl_xor(pr, off, 64);
    if (lane == 0) scws[task] = pr * 0.08838834764831845f;  // 1/sqrt(128)
  }
}

// ---------- epilogue C: softmax over K=20, weighted context sum ----------
__global__ __launch_bounds__(128) void kfinalC(
    const float* __restrict__ Vws, const float* __restrict__ scws,
    float* __restrict__ out) {
  const int b = blockIdx.x;
  const int t = threadIdx.x;   // t = d
  float sc[20];
  float m = -3.0e38f;
  #pragma unroll
  for (int i = 0; i < 20; ++i) { sc[i] = scws[b * 20 + i]; m = fmaxf(m, sc[i]); }
  float s = 0.f;
  #pragma unroll
  for (int i = 0; i < 20; ++i) { sc[i] = expf(sc[i] - m); s += sc[i]; }
  const float inv = 1.0f / s;
  float acc = 0.f;
  #pragma unroll 4
  for (int i = 0; i < 20; ++i)
    acc = fmaf(sc[i] * inv, Vws[(size_t)(b * 20 + i) * 128 + t], acc);
  out[b * 128 + t] = acc;
}

extern "C" void kernel_launch(void* const* d_in, const int* in_sizes, int n_in,
                              void* d_out, int out_size, void* d_ws, size_t ws_size,
                              hipStream_t stream) {
  (void)in_sizes; (void)n_in; (void)out_size; (void)ws_size;
  const float* pe = (const float*)d_in[0];
  const float* ge = (const float*)d_in[1];
  const float* Wq = (const float*)d_in[2];
  const float* bq = (const float*)d_in[3];
  const float* Wk = (const float*)d_in[4];
  const float* bk = (const float*)d_in[5];
  const float* Wv = (const float*)d_in[6];
  const float* bvp = (const float*)d_in[7];
  const float* W1 = (const float*)d_in[8];
  const float* b1 = (const float*)d_in[9];
  const float* w2 = (const float*)d_in[10];
  // d_in[11] = b2: uniform over n -> cancels in argmax; absent from output path.

  char* w = (char*)d_ws;
  double* Wfd = (double*)w;                              // 262144 B
  double* qbT = (double*)(w + 262144);                   // 65536 B
  float* Qm = (float*)(w + 327680);                      // 32768 B
  unsigned long long* cells =
      (unsigned long long*)(w + 360448);                 // 10240 B
  double2* c12 = (double2*)(w + 370688);                 // 2048 B
  double* simd = (double*)(w + 372736);                  // 10,240,000 B
  float* sim2f = (float*)(w + 10612736);                 // 5,120,000 B
  float* Vws = (float*)(w + 15732736);                   // 655,360 B
  float* scws = (float*)(w + 16388096);                  // 5,120 B (~16.4 MB total)
  float* out = (float*)d_out;

  kprep<<<dim3(321), dim3(128), 0, stream>>>(pe, Wq, bq, Wk, bk, W1, b1, w2,
                                             Wfd, qbT, Qm, cells, c12);
  kfused<<<dim3(1250), dim3(256), 0, stream>>>(ge, Wfd, qbT, c12, simd, sim2f);
  ksel2<<<dim3(1976), dim3(256), 0, stream>>>(simd, sim2f, cells);
  kfinalV<<<dim3(1280), dim3(256), 0, stream>>>(ge, Wv, bvp, Qm, cells, Vws, scws);
  kfinalC<<<dim3(64), dim3(128), 0, stream>>>(Vws, scws, out);
}

// Round 11
// 360.523 us; speedup vs baseline: 1.1084x; 1.0058x over previous
//
#include <hip/hip_runtime.h>

#define NG 20000
#define BOFF 12800000u   // flat-index offset of batch b+32: 32*K*N

// ---------- JAX threefry2x32, key = (0, 42) ----------
__device__ __forceinline__ void threefry2x32(unsigned x0, unsigned x1,
                                             unsigned& o0, unsigned& o1) {
  const unsigned ks0 = 0u;
  const unsigned ks1 = 42u;
  const unsigned ks2 = 0x1BD11BDAu ^ 0u ^ 42u;
  x0 += ks0; x1 += ks1;
#define TFR(r) { x0 += x1; x1 = (x1 << (r)) | (x1 >> (32 - (r))); x1 ^= x0; }
  TFR(13) TFR(15) TFR(26) TFR(6)
  x0 += ks1; x1 += ks2 + 1u;
  TFR(17) TFR(29) TFR(16) TFR(24)
  x0 += ks2; x1 += ks0 + 2u;
  TFR(13) TFR(15) TFR(26) TFR(6)
  x0 += ks0; x1 += ks1 + 3u;
  TFR(17) TFR(29) TFR(16) TFR(24)
  x0 += ks1; x1 += ks2 + 4u;
  TFR(13) TFR(15) TFR(26) TFR(6)
  x0 += ks2; x1 += ks0 + 5u;
#undef TFR
  o0 = x0; o1 = x1;
}

// JAX threefry_partitionable: bits(i) = o0 ^ o1 of threefry((0,42),(0,i))
__device__ __forceinline__ unsigned tfbits(unsigned ctr) {
  unsigned o0, o1;
  threefry2x32(0u, ctr, o0, o1);
  return o0 ^ o1;
}

// fp32 fast-screen gumbel (hw log path); abs err vs fp64 < ~1e-5
__device__ __forceinline__ float gumbel32(unsigned bits) {
  float f = __uint_as_float((bits >> 9) | 0x3f800000u) - 1.0f;
  float u = fmaxf(f, 1.17549435e-38f);
  return -__logf(-__logf(u));
}

// exact fp64 gumbel; u is a 23-bit dyadic rational, exact in double
__device__ __forceinline__ double gumbel64(unsigned bits) {
  float f = __uint_as_float((bits >> 9) | 0x3f800000u) - 1.0f;
  double u = (double)fmaxf(f, 1.17549435e-38f);
  return -log(-log(u));
}

// pack fp64 score (top 49 monotone bits) + 15-bit (32767-n): u64 max == (score, then smaller n)
__device__ __forceinline__ unsigned long long packcell(double v, int n) {
  unsigned long long u = (unsigned long long)__double_as_longlong(v);
  u = (u >> 63) ? ~u : (u | 0x8000000000000000ull);
  return (u & 0xFFFFFFFFFFFF8000ull) | (unsigned long long)(32767 - n);
}

// ---------- prep: Wf=Wk@W1k (fp64 math, fp32 store), Q, qbT; c12; zero cells ----------
__global__ __launch_bounds__(128) void kprep(
    const float* __restrict__ pe, const float* __restrict__ Wq,
    const float* __restrict__ bq, const float* __restrict__ Wk,
    const float* __restrict__ bk, const float* __restrict__ W1,
    const float* __restrict__ b1, const float* __restrict__ w2,
    float* __restrict__ Wf32, double* __restrict__ qbT,
    float* __restrict__ Qm, unsigned long long* __restrict__ cells,
    double2* __restrict__ c12) {
  __shared__ float L[512];
  __shared__ double Ld[128];
  const int t = threadIdx.x;
  const int bid = blockIdx.x;
  if (bid < 256) {
    L[t] = Wk[bid * 128 + t];
    __syncthreads();
    double acc = 0.0;
    #pragma unroll 8
    for (int j = 0; j < 128; ++j)
      acc = fma((double)L[j], (double)W1[(128 + j) * 128 + t], acc);
    Wf32[bid * 128 + t] = (float)acc;
  } else if (bid < 320) {
    const int b = bid - 256;
    #pragma unroll
    for (int i = 0; i < 4; ++i) L[t + 128 * i] = pe[b * 512 + t + 128 * i];
    __syncthreads();
    double q = (double)bq[t];
    #pragma unroll 4
    for (int f = 0; f < 512; ++f)
      q = fma((double)L[f], (double)Wq[f * 128 + t], q);
    Qm[b * 128 + t] = (float)q;   // epilogue path stays fp32
    Ld[t] = q;
    __syncthreads();
    // qb[b,d=t] = Q@W1[:128] + b1 + bk@W1[128:]; store transposed qbT[d][b]
    double acc = (double)b1[t];
    #pragma unroll 4
    for (int j = 0; j < 128; ++j) {
      acc = fma(Ld[j], (double)W1[j * 128 + t], acc);
      acc = fma((double)bk[j], (double)W1[(128 + j) * 128 + t], acc);
    }
    qbT[t * 64 + b] = acc;
  } else {
    for (int i = t; i < 1280; i += 128) cells[i] = 0ull;
    const double w2d = (double)w2[t];
    c12[t] = make_double2(0.55 * w2d, 0.45 * w2d);
  }
}

// ---------- fused kp(fp32 GEMM) + sim(fp64 from fp32 kp) ----------
// block = 256 threads, 16 genes. Phase 1: thread (d=t&127, h=t>>7) accumulates
// fp32 kp[d][g] for genes h*8..+8, 2-stage register pipeline, no barriers.
// Phase 2: kp -> LDS (float); wave wv computes fp64 sim for genes
// {wv, wv+4, wv+8, wv+12}, lane = batch.
__global__ __launch_bounds__(256) void kfused(
    const float* __restrict__ ge, const float* __restrict__ Wf32,
    const double* __restrict__ qbT, const double2* __restrict__ c12,
    double* __restrict__ simd, float* __restrict__ sim2f) {
  __shared__ float kpL[2048];    // kp[16][128]
  __shared__ double simL[1088];  // sim[64][17]
  const int t = threadIdx.x;
  const int d = t & 127;
  const int h = t >> 7;
  const int wv = t >> 6;
  const int lane = t & 63;
  const int g0 = blockIdx.x * 16;     // 1250 blocks * 16 genes

  float acc[8];
  #pragma unroll
  for (int g = 0; g < 8; ++g) acc[g] = 0.f;
  const float* gbase = ge + (size_t)(g0 + h * 8) * 256;
  const float* wbase = Wf32 + d;

  float4 ac[8];
  float wc[4];
  #pragma unroll
  for (int g = 0; g < 8; ++g) ac[g] = *(const float4*)(gbase + g * 256);
  #pragma unroll
  for (int j = 0; j < 4; ++j) wc[j] = wbase[j * 128];

  for (int f0 = 0; f0 < 256; f0 += 4) {
    float4 an[8];
    float wn[4];
    if (f0 < 252) {
      #pragma unroll
      for (int j = 0; j < 4; ++j) wn[j] = wbase[(f0 + 4 + j) * 128];
      #pragma unroll
      for (int g = 0; g < 8; ++g)
        an[g] = *(const float4*)(gbase + g * 256 + f0 + 4);
    }
    #pragma unroll
    for (int j = 0; j < 4; ++j) {
      const float wj = wc[j];
      acc[0] = fmaf((&ac[0].x)[j], wj, acc[0]);
      acc[1] = fmaf((&ac[1].x)[j], wj, acc[1]);
      acc[2] = fmaf((&ac[2].x)[j], wj, acc[2]);
      acc[3] = fmaf((&ac[3].x)[j], wj, acc[3]);
      acc[4] = fmaf((&ac[4].x)[j], wj, acc[4]);
      acc[5] = fmaf((&ac[5].x)[j], wj, acc[5]);
      acc[6] = fmaf((&ac[6].x)[j], wj, acc[6]);
      acc[7] = fmaf((&ac[7].x)[j], wj, acc[7]);
    }
    #pragma unroll
    for (int g = 0; g < 8; ++g) ac[g] = an[g];
    #pragma unroll
    for (int j = 0; j < 4; ++j) wc[j] = wn[j];
  }

  // ---- phase 2: kp -> LDS, then fp64 sim (4 genes/wave, lane = batch) ----
  #pragma unroll
  for (int g = 0; g < 8; ++g) kpL[(h * 8 + g) * 128 + d] = acc[g];
  __syncthreads();

  double s[4];
  #pragma unroll
  for (int j = 0; j < 4; ++j) s[j] = 0.0;
  for (int dd = 0; dd < 128; ++dd) {
    const double2 cc = c12[dd];                   // uniform -> s_load
    const double qv = qbT[dd * 64 + lane];        // coalesced, L1-hot
    #pragma unroll
    for (int j = 0; j < 4; ++j) {
      const double kv = (double)kpL[(wv + j * 4) * 128 + dd];  // broadcast
      const double tt = qv + kv;
      s[j] = fma(tt, cc.x, s[j]);
      s[j] = fma(fabs(tt), cc.y, s[j]);
    }
  }
  #pragma unroll
  for (int j = 0; j < 4; ++j) simL[lane * 17 + (wv + j * 4)] = s[j];
  __syncthreads();

  // write-out: thread -> (b = t>>2, quarter j2 = t&3): 4 doubles + 4 floats
  {
    const int b = t >> 2, j2 = t & 3;
    const double v0 = simL[b * 17 + j2 * 4 + 0];
    const double v1 = simL[b * 17 + j2 * 4 + 1];
    const double v2 = simL[b * 17 + j2 * 4 + 2];
    const double v3 = simL[b * 17 + j2 * 4 + 3];
    double* dst = simd + (size_t)b * NG + g0 + j2 * 4;
    *(double2*)dst = make_double2(v0, v1);
    *(double2*)(dst + 2) = make_double2(v2, v3);
    float4 f4;
    f4.x = (float)(2.0 * v0); f4.y = (float)(2.0 * v1);
    f4.z = (float)(2.0 * v2); f4.w = (float)(2.0 * v3);
    *(float4*)(sim2f + (size_t)b * NG + g0 + j2 * 4) = f4;
  }
}

// ---------- selection: single-pass fp32 top-2 screen (sim2f), fp64 exact at end ----------
__global__ __launch_bounds__(256) void ksel2(
    const double* __restrict__ simd, const float* __restrict__ sim2f,
    unsigned long long* __restrict__ cells) {
  const int t = threadIdx.x;
  const int wv = t >> 6;
  const int lane = t & 63;
  const int p = (int)(blockIdx.x & 7) * 4 + wv;   // pair 0..31
  const int c = (int)(blockIdx.x >> 3);           // chunk 0..246
  const int n0 = c * 81;
  const int nEnd = min(n0 + 81, NG);
  const int k = lane % 20;
  const int gi = lane / 20;
  const bool active = lane < 60;
  const double* sdA = simd + (size_t)p * NG;
  const double* sdB = simd + (size_t)(p + 32) * NG;
  const float* seA = sim2f + (size_t)p * NG;
  const float* seB = sim2f + (size_t)(p + 32) * NG;
  const unsigned kbase = (unsigned)(p * 20 + k) * (unsigned)NG;

  float m1A = -3e38f, m2A = -3e38f, m1B = -3e38f, m2B = -3e38f;
  int n1A = -1, n2A = -1, n1B = -1, n2B = -1;
  unsigned c1A = 0, c2A = 0, c1B = 0, c2B = 0;

  for (int it = 0; it < 27; ++it) {
    const int n = n0 + it * 3 + gi;
    const bool v = active && (n < nEnd);
    const int nc = v ? n : n0;
    const unsigned idxA = kbase + (unsigned)nc;
    const unsigned bA = tfbits(idxA);
    const unsigned bB = tfbits(idxA + BOFF);
    const float s2A = v ? seA[nc] : -3e38f;
    const float s2B = v ? seB[nc] : -3e38f;
    const float sA = s2A + gumbel32(bA);
    const float sB = s2B + gumbel32(bB);
    if (sA > m1A) { m2A = m1A; n2A = n1A; c2A = c1A; m1A = sA; n1A = n; c1A = bA; }
    else if (sA > m2A) { m2A = sA; n2A = n; c2A = bA; }
    if (sB > m1B) { m2B = m1B; n2B = n1B; c2B = c1B; m1B = sB; n1B = n; c1B = bB; }
    else if (sB > m2B) { m2B = sB; n2B = n; c2B = bB; }
  }

  // exact fp64 for the fp32 winner (+ runner-up iff ambiguous: gap < 1e-4 >> 1e-5 screen err)
  unsigned long long pbA = 0ull, pbB = 0ull;
  if (n1A >= 0) {
    pbA = packcell(2.0 * sdA[n1A] + gumbel64(c1A), n1A);
    if (n2A >= 0 && (m1A - m2A) < 1e-4f) {
      const unsigned long long u2 = packcell(2.0 * sdA[n2A] + gumbel64(c2A), n2A);
      if (u2 > pbA) pbA = u2;
    }
  }
  if (n1B >= 0) {
    pbB = packcell(2.0 * sdB[n1B] + gumbel64(c1B), n1B);
    if (n2B >= 0 && (m1B - m2B) < 1e-4f) {
      const unsigned long long u2 = packcell(2.0 * sdB[n2B] + gumbel64(c2B), n2B);
      if (u2 > pbB) pbB = u2;
    }
  }

  // fold gi slots (lanes +20, +40), then one atomic per (batch, k)
  #pragma unroll
  for (int sh = 20; sh <= 40; sh += 20) {
    const unsigned long long oA = __shfl(pbA, lane + sh, 64);
    const unsigned long long oB = __shfl(pbB, lane + sh, 64);
    if (lane < 20) {
      if (oA > pbA) pbA = oA;
      if (oB > pbB) pbB = oB;
    }
  }
  if (lane < 20 && pbA) atomicMax(&cells[p * 20 + lane], pbA);
  if (lane < 20 && pbB) atomicMax(&cells[(p + 32) * 20 + lane], pbB);
}

// ---------- epilogue (fp32): 5 interleaved V-GEMVs per wave, softmax over K, context ----------
__global__ __launch_bounds__(256) void kfinal(
    const float* __restrict__ ge, const float* __restrict__ Wv,
    const float* __restrict__ bv, const float* __restrict__ Qm,
    const unsigned long long* __restrict__ cells, float* __restrict__ out) {
  const int b = blockIdx.x;
  const int t = threadIdx.x;
  const int wv = t >> 6;
  const int lane = t & 63;
  __shared__ float sc[20];
  __shared__ float ctxp[4][128];
  const float2 qv = ((const float2*)(Qm + b * 128))[lane];
  const float2 bvv = ((const float2*)bv)[lane];
  const float* gr[5];
  float2 V[5];
  #pragma unroll
  for (int j = 0; j < 5; ++j) {
    const unsigned long long cell = cells[b * 20 + wv * 5 + j];
    const int n = 32767 - (int)(cell & 0x7FFFull);
    gr[j] = ge + (size_t)n * 256;
    V[j] = bvv;
  }
  for (int f = 0; f < 256; f += 4) {
    const float2 w0 = ((const float2*)(Wv + (size_t)(f + 0) * 128))[lane];
    const float2 w1 = ((const float2*)(Wv + (size_t)(f + 1) * 128))[lane];
    const float2 w2_ = ((const float2*)(Wv + (size_t)(f + 2) * 128))[lane];
    const float2 w3 = ((const float2*)(Wv + (size_t)(f + 3) * 128))[lane];
    #pragma unroll
    for (int j = 0; j < 5; ++j) {
      const float4 gv = *(const float4*)(gr[j] + f);   // uniform -> s_load
      V[j].x = fmaf(gv.x, w0.x, V[j].x); V[j].y = fmaf(gv.x, w0.y, V[j].y);
      V[j].x = fmaf(gv.y, w1.x, V[j].x); V[j].y = fmaf(gv.y, w1.y, V[j].y);
      V[j].x = fmaf(gv.z, w2_.x, V[j].x); V[j].y = fmaf(gv.z, w2_.y, V[j].y);
      V[j].x = fmaf(gv.w, w3.x, V[j].x); V[j].y = fmaf(gv.w, w3.y, V[j].y);
    }
  }
  #pragma unroll
  for (int j = 0; j < 5; ++j) {
    float pr = qv.x * V[j].x + qv.y * V[j].y;
    #pragma unroll
    for (int off = 32; off; off >>= 1) pr += __shfl_xor(pr, off, 64);
    if (lane == 0) sc[wv * 5 + j] = pr * 0.08838834764831845f;  // 1/sqrt(128)
  }
  __syncthreads();
  float m = -3.0e38f;
  #pragma unroll
  for (int i = 0; i < 20; ++i) m = fmaxf(m, sc[i]);
  float s = 0.f;
  #pragma unroll
  for (int i = 0; i < 20; ++i) s += expf(sc[i] - m);
  const float inv = 1.0f / s;
  float c0 = 0.f, c1 = 0.f;
  #pragma unroll
  for (int j = 0; j < 5; ++j) {
    const float wk = expf(sc[wv * 5 + j] - m) * inv;
    c0 = fmaf(wk, V[j].x, c0);
    c1 = fmaf(wk, V[j].y, c1);
  }
  ctxp[wv][2 * lane] = c0;
  ctxp[wv][2 * lane + 1] = c1;
  __syncthreads();
  if (t < 128)
    out[b * 128 + t] = (ctxp[0][t] + ctxp[1][t]) + (ctxp[2][t] + ctxp[3][t]);
}

extern "C" void kernel_launch(void* const* d_in, const int* in_sizes, int n_in,
                              void* d_out, int out_size, void* d_ws, size_t ws_size,
                              hipStream_t stream) {
  (void)in_sizes; (void)n_in; (void)out_size; (void)ws_size;
  const float* pe = (const float*)d_in[0];
  const float* ge = (const float*)d_in[1];
  const float* Wq = (const float*)d_in[2];
  const float* bq = (const float*)d_in[3];
  const float* Wk = (const float*)d_in[4];
  const float* bk = (const float*)d_in[5];
  const float* Wv = (const float*)d_in[6];
  const float* bvp = (const float*)d_in[7];
  const float* W1 = (const float*)d_in[8];
  const float* b1 = (const float*)d_in[9];
  const float* w2 = (const float*)d_in[10];
  // d_in[11] = b2: uniform over n -> cancels in argmax; absent from output path.

  char* w = (char*)d_ws;
  float* Wf32 = (float*)w;                               // 131072 B
  double* qbT = (double*)(w + 131072);                   // 65536 B
  float* Qm = (float*)(w + 196608);                      // 32768 B
  unsigned long long* cells =
      (unsigned long long*)(w + 229376);                 // 10240 B
  double2* c12 = (double2*)(w + 239616);                 // 2048 B
  double* simd = (double*)(w + 241664);                  // 10,240,000 B
  float* sim2f = (float*)(w + 10481664);                 // 5,120,000 B (~15.6 MB total)
  float* out = (float*)d_out;

  kprep<<<dim3(321), dim3(128), 0, stream>>>(pe, Wq, bq, Wk, bk, W1, b1, w2,
                                             Wf32, qbT, Qm, cells, c12);
  kfused<<<dim3(1250), dim3(256), 0, stream>>>(ge, Wf32, qbT, c12, simd, sim2f);
  ksel2<<<dim3(1976), dim3(256), 0, stream>>>(simd, sim2f, cells);
  kfinal<<<dim3(64), dim3(256), 0, stream>>>(ge, Wv, bvp, Qm, cells, out);
}

// Round 12
// 289.277 us; speedup vs baseline: 1.3814x; 1.2463x over previous
//
#include <hip/hip_runtime.h>

#define NG 20000
#define BOFF 12800000u   // flat-index offset of batch b+32: 32*K*N

// ---------- JAX threefry2x32, key = (0, 42) ----------
__device__ __forceinline__ void threefry2x32(unsigned x0, unsigned x1,
                                             unsigned& o0, unsigned& o1) {
  const unsigned ks0 = 0u;
  const unsigned ks1 = 42u;
  const unsigned ks2 = 0x1BD11BDAu ^ 0u ^ 42u;
  x0 += ks0; x1 += ks1;
#define TFR(r) { x0 += x1; x1 = (x1 << (r)) | (x1 >> (32 - (r))); x1 ^= x0; }
  TFR(13) TFR(15) TFR(26) TFR(6)
  x0 += ks1; x1 += ks2 + 1u;
  TFR(17) TFR(29) TFR(16) TFR(24)
  x0 += ks2; x1 += ks0 + 2u;
  TFR(13) TFR(15) TFR(26) TFR(6)
  x0 += ks0; x1 += ks1 + 3u;
  TFR(17) TFR(29) TFR(16) TFR(24)
  x0 += ks1; x1 += ks2 + 4u;
  TFR(13) TFR(15) TFR(26) TFR(6)
  x0 += ks2; x1 += ks0 + 5u;
#undef TFR
  o0 = x0; o1 = x1;
}

// JAX threefry_partitionable: bits(i) = o0 ^ o1 of threefry((0,42),(0,i))
__device__ __forceinline__ unsigned tfbits(unsigned ctr) {
  unsigned o0, o1;
  threefry2x32(0u, ctr, o0, o1);
  return o0 ^ o1;
}

// fp32 fast-screen gumbel (hw log path); abs err vs fp64 < ~1e-5
__device__ __forceinline__ float gumbel32(unsigned bits) {
  float f = __uint_as_float((bits >> 9) | 0x3f800000u) - 1.0f;
  float u = fmaxf(f, 1.17549435e-38f);
  return -__logf(-__logf(u));
}

// exact fp64 gumbel; u is a 23-bit dyadic rational, exact in double
__device__ __forceinline__ double gumbel64(unsigned bits) {
  float f = __uint_as_float((bits >> 9) | 0x3f800000u) - 1.0f;
  double u = (double)fmaxf(f, 1.17549435e-38f);
  return -log(-log(u));
}

// pack fp64 score (top 49 monotone bits) + 15-bit (32767-n): u64 max == (score, then smaller n)
__device__ __forceinline__ unsigned long long packcell(double v, int n) {
  unsigned long long u = (unsigned long long)__double_as_longlong(v);
  u = (u >> 63) ? ~u : (u | 0x8000000000000000ull);
  return (u & 0xFFFFFFFFFFFF8000ull) | (unsigned long long)(32767 - n);
}

// ---------- prep: Wf=Wk@W1k (fp64 math, fp32 store), Q, qbT; c12; zero cells ----------
__global__ __launch_bounds__(128) void kprep(
    const float* __restrict__ pe, const float* __restrict__ Wq,
    const float* __restrict__ bq, const float* __restrict__ Wk,
    const float* __restrict__ bk, const float* __restrict__ W1,
    const float* __restrict__ b1, const float* __restrict__ w2,
    float* __restrict__ Wf32, double* __restrict__ qbT,
    float* __restrict__ Qm, unsigned long long* __restrict__ cells,
    double2* __restrict__ c12) {
  __shared__ float L[512];
  __shared__ double Ld[128];
  const int t = threadIdx.x;
  const int bid = blockIdx.x;
  if (bid < 256) {
    L[t] = Wk[bid * 128 + t];
    __syncthreads();
    double acc = 0.0;
    #pragma unroll 8
    for (int j = 0; j < 128; ++j)
      acc = fma((double)L[j], (double)W1[(128 + j) * 128 + t], acc);
    Wf32[bid * 128 + t] = (float)acc;
  } else if (bid < 320) {
    const int b = bid - 256;
    #pragma unroll
    for (int i = 0; i < 4; ++i) L[t + 128 * i] = pe[b * 512 + t + 128 * i];
    __syncthreads();
    double q = (double)bq[t];
    #pragma unroll 4
    for (int f = 0; f < 512; ++f)
      q = fma((double)L[f], (double)Wq[f * 128 + t], q);
    Qm[b * 128 + t] = (float)q;   // epilogue path stays fp32
    Ld[t] = q;
    __syncthreads();
    // qb[b,d=t] = Q@W1[:128] + b1 + bk@W1[128:]; store transposed qbT[d][b]
    double acc = (double)b1[t];
    #pragma unroll 4
    for (int j = 0; j < 128; ++j) {
      acc = fma(Ld[j], (double)W1[j * 128 + t], acc);
      acc = fma((double)bk[j], (double)W1[(128 + j) * 128 + t], acc);
    }
    qbT[t * 64 + b] = acc;
  } else {
    for (int i = t; i < 1280; i += 128) cells[i] = 0ull;
    const double w2d = (double)w2[t];
    c12[t] = make_double2(0.55 * w2d, 0.45 * w2d);
  }
}

// ---------- fused kp(fp32) + sim(fp64): ge tile burst-staged to LDS ----------
// block = 256 threads, 16 genes. Phase 1: wave wv owns genes wv*4..wv*4+3;
// thread owns d = lane and lane+64. Genes via same-address ds_read_b128
// broadcast; Wf32 via depth-2 coalesced register stream. Per-acc f-order
// ascending, fp32 fmaf -> kp bit-identical to R11. Phase 2: fp64 sim for
// genes {wv, wv+4, wv+8, wv+12}, lane = batch (identical to R11).
__global__ __launch_bounds__(256) void kfused(
    const float* __restrict__ ge, const float* __restrict__ Wf32,
    const double* __restrict__ qbT, const double2* __restrict__ c12,
    double* __restrict__ simd, float* __restrict__ sim2f) {
  __shared__ double SBd[2048];   // phase1: geL (16 KB as float); phase2: simL[1088]
  __shared__ float kpL[2048];    // kp[16][128]
  float* geL = (float*)SBd;
  double* simL = SBd;
  const int t = threadIdx.x;
  const int wv = t >> 6;
  const int lane = t & 63;
  const int g0 = blockIdx.x * 16;     // 1250 blocks * 16 genes

  // stage ge tile (16 genes x 256 f) -> LDS: 4 independent float4 per thread
  {
    const float4* src = (const float4*)(ge + (size_t)g0 * 256);
    float4* dst = (float4*)geL;
    #pragma unroll
    for (int i = 0; i < 4; ++i) dst[t + i * 256] = src[t + i * 256];
  }
  __syncthreads();

  // ---- phase 1: fp32 GEMM from LDS genes + streamed Wf32 ----
  float acc[4][2];
  #pragma unroll
  for (int j = 0; j < 4; ++j) { acc[j][0] = 0.f; acc[j][1] = 0.f; }
  const float* wb0 = Wf32 + lane;
  const float* wb1 = Wf32 + lane + 64;
  const float* gL = geL + wv * 4 * 256;

  float wc0[4], wc1[4];
  #pragma unroll
  for (int ff = 0; ff < 4; ++ff) {
    wc0[ff] = wb0[ff * 128];
    wc1[ff] = wb1[ff * 128];
  }
  for (int f0 = 0; f0 < 256; f0 += 4) {
    float wn0[4], wn1[4];
    if (f0 < 252) {
      #pragma unroll
      for (int ff = 0; ff < 4; ++ff) {
        wn0[ff] = wb0[(f0 + 4 + ff) * 128];
        wn1[ff] = wb1[(f0 + 4 + ff) * 128];
      }
    }
    #pragma unroll
    for (int j = 0; j < 4; ++j) {
      const float4 gv = *(const float4*)(gL + j * 256 + f0);  // ds_read_b128 bcast
      acc[j][0] = fmaf(gv.x, wc0[0], acc[j][0]);
      acc[j][1] = fmaf(gv.x, wc1[0], acc[j][1]);
      acc[j][0] = fmaf(gv.y, wc0[1], acc[j][0]);
      acc[j][1] = fmaf(gv.y, wc1[1], acc[j][1]);
      acc[j][0] = fmaf(gv.z, wc0[2], acc[j][0]);
      acc[j][1] = fmaf(gv.z, wc1[2], acc[j][1]);
      acc[j][0] = fmaf(gv.w, wc0[3], acc[j][0]);
      acc[j][1] = fmaf(gv.w, wc1[3], acc[j][1]);
    }
    #pragma unroll
    for (int ff = 0; ff < 4; ++ff) { wc0[ff] = wn0[ff]; wc1[ff] = wn1[ff]; }
  }

  __syncthreads();   // geL reads done (SBd about to be reused as simL)
  #pragma unroll
  for (int j = 0; j < 4; ++j) {
    kpL[(wv * 4 + j) * 128 + lane] = acc[j][0];
    kpL[(wv * 4 + j) * 128 + lane + 64] = acc[j][1];
  }
  __syncthreads();

  // ---- phase 2: fp64 sim (4 genes/wave, lane = batch) — identical to R11 ----
  double s[4];
  #pragma unroll
  for (int j = 0; j < 4; ++j) s[j] = 0.0;
  for (int dd = 0; dd < 128; ++dd) {
    const double2 cc = c12[dd];                   // uniform -> s_load
    const double qv = qbT[dd * 64 + lane];        // coalesced, L1-hot
    #pragma unroll
    for (int j = 0; j < 4; ++j) {
      const double kv = (double)kpL[(wv + j * 4) * 128 + dd];  // broadcast
      const double tt = qv + kv;
      s[j] = fma(tt, cc.x, s[j]);
      s[j] = fma(fabs(tt), cc.y, s[j]);
    }
  }
  #pragma unroll
  for (int j = 0; j < 4; ++j) simL[lane * 17 + (wv + j * 4)] = s[j];
  __syncthreads();

  // write-out: thread -> (b = t>>2, quarter j2 = t&3): 4 doubles + 4 floats
  {
    const int b = t >> 2, j2 = t & 3;
    const double v0 = simL[b * 17 + j2 * 4 + 0];
    const double v1 = simL[b * 17 + j2 * 4 + 1];
    const double v2 = simL[b * 17 + j2 * 4 + 2];
    const double v3 = simL[b * 17 + j2 * 4 + 3];
    double* dst = simd + (size_t)b * NG + g0 + j2 * 4;
    *(double2*)dst = make_double2(v0, v1);
    *(double2*)(dst + 2) = make_double2(v2, v3);
    float4 f4;
    f4.x = (float)(2.0 * v0); f4.y = (float)(2.0 * v1);
    f4.z = (float)(2.0 * v2); f4.w = (float)(2.0 * v3);
    *(float4*)(sim2f + (size_t)b * NG + g0 + j2 * 4) = f4;
  }
}

// ---------- selection: single-pass fp32 top-2 screen (sim2f), fp64 exact at end ----------
__global__ __launch_bounds__(256) void ksel2(
    const double* __restrict__ simd, const float* __restrict__ sim2f,
    unsigned long long* __restrict__ cells) {
  const int t = threadIdx.x;
  const int wv = t >> 6;
  const int lane = t & 63;
  const int p = (int)(blockIdx.x & 7) * 4 + wv;   // pair 0..31
  const int c = (int)(blockIdx.x >> 3);           // chunk 0..246
  const int n0 = c * 81;
  const int nEnd = min(n0 + 81, NG);
  const int k = lane % 20;
  const int gi = lane / 20;
  const bool active = lane < 60;
  const double* sdA = simd + (size_t)p * NG;
  const double* sdB = simd + (size_t)(p + 32) * NG;
  const float* seA = sim2f + (size_t)p * NG;
  const float* seB = sim2f + (size_t)(p + 32) * NG;
  const unsigned kbase = (unsigned)(p * 20 + k) * (unsigned)NG;

  float m1A = -3e38f, m2A = -3e38f, m1B = -3e38f, m2B = -3e38f;
  int n1A = -1, n2A = -1, n1B = -1, n2B = -1;
  unsigned c1A = 0, c2A = 0, c1B = 0, c2B = 0;

  for (int it = 0; it < 27; ++it) {
    const int n = n0 + it * 3 + gi;
    const bool v = active && (n < nEnd);
    const int nc = v ? n : n0;
    const unsigned idxA = kbase + (unsigned)nc;
    const unsigned bA = tfbits(idxA);
    const unsigned bB = tfbits(idxA + BOFF);
    const float s2A = v ? seA[nc] : -3e38f;
    const float s2B = v ? seB[nc] : -3e38f;
    const float sA = s2A + gumbel32(bA);
    const float sB = s2B + gumbel32(bB);
    if (sA > m1A) { m2A = m1A; n2A = n1A; c2A = c1A; m1A = sA; n1A = n; c1A = bA; }
    else if (sA > m2A) { m2A = sA; n2A = n; c2A = bA; }
    if (sB > m1B) { m2B = m1B; n2B = n1B; c2B = c1B; m1B = sB; n1B = n; c1B = bB; }
    else if (sB > m2B) { m2B = sB; n2B = n; c2B = bB; }
  }

  // exact fp64 for the fp32 winner (+ runner-up iff ambiguous: gap < 1e-4 >> 1e-5 screen err)
  unsigned long long pbA = 0ull, pbB = 0ull;
  if (n1A >= 0) {
    pbA = packcell(2.0 * sdA[n1A] + gumbel64(c1A), n1A);
    if (n2A >= 0 && (m1A - m2A) < 1e-4f) {
      const unsigned long long u2 = packcell(2.0 * sdA[n2A] + gumbel64(c2A), n2A);
      if (u2 > pbA) pbA = u2;
    }
  }
  if (n1B >= 0) {
    pbB = packcell(2.0 * sdB[n1B] + gumbel64(c1B), n1B);
    if (n2B >= 0 && (m1B - m2B) < 1e-4f) {
      const unsigned long long u2 = packcell(2.0 * sdB[n2B] + gumbel64(c2B), n2B);
      if (u2 > pbB) pbB = u2;
    }
  }

  // fold gi slots (lanes +20, +40), then one atomic per (batch, k)
  #pragma unroll
  for (int sh = 20; sh <= 40; sh += 20) {
    const unsigned long long oA = __shfl(pbA, lane + sh, 64);
    const unsigned long long oB = __shfl(pbB, lane + sh, 64);
    if (lane < 20) {
      if (oA > pbA) pbA = oA;
      if (oB > pbB) pbB = oB;
    }
  }
  if (lane < 20 && pbA) atomicMax(&cells[p * 20 + lane], pbA);
  if (lane < 20 && pbB) atomicMax(&cells[(p + 32) * 20 + lane], pbB);
}

// ---------- epilogue (fp32): 5 interleaved V-GEMVs per wave, softmax over K, context ----------
__global__ __launch_bounds__(256) void kfinal(
    const float* __restrict__ ge, const float* __restrict__ Wv,
    const float* __restrict__ bv, const float* __restrict__ Qm,
    const unsigned long long* __restrict__ cells, float* __restrict__ out) {
  const int b = blockIdx.x;
  const int t = threadIdx.x;
  const int wv = t >> 6;
  const int lane = t & 63;
  __shared__ float sc[20];
  __shared__ float ctxp[4][128];
  const float2 qv = ((const float2*)(Qm + b * 128))[lane];
  const float2 bvv = ((const float2*)bv)[lane];
  const float* gr[5];
  float2 V[5];
  #pragma unroll
  for (int j = 0; j < 5; ++j) {
    const unsigned long long cell = cells[b * 20 + wv * 5 + j];
    const int n = 32767 - (int)(cell & 0x7FFFull);
    gr[j] = ge + (size_t)n * 256;
    V[j] = bvv;
  }
  for (int f = 0; f < 256; f += 4) {
    const float2 w0 = ((const float2*)(Wv + (size_t)(f + 0) * 128))[lane];
    const float2 w1 = ((const float2*)(Wv + (size_t)(f + 1) * 128))[lane];
    const float2 w2_ = ((const float2*)(Wv + (size_t)(f + 2) * 128))[lane];
    const float2 w3 = ((const float2*)(Wv + (size_t)(f + 3) * 128))[lane];
    #pragma unroll
    for (int j = 0; j < 5; ++j) {
      const float4 gv = *(const float4*)(gr[j] + f);   // uniform -> s_load
      V[j].x = fmaf(gv.x, w0.x, V[j].x); V[j].y = fmaf(gv.x, w0.y, V[j].y);
      V[j].x = fmaf(gv.y, w1.x, V[j].x); V[j].y = fmaf(gv.y, w1.y, V[j].y);
      V[j].x = fmaf(gv.z, w2_.x, V[j].x); V[j].y = fmaf(gv.z, w2_.y, V[j].y);
      V[j].x = fmaf(gv.w, w3.x, V[j].x); V[j].y = fmaf(gv.w, w3.y, V[j].y);
    }
  }
  #pragma unroll
  for (int j = 0; j < 5; ++j) {
    float pr = qv.x * V[j].x + qv.y * V[j].y;
    #pragma unroll
    for (int off = 32; off; off >>= 1) pr += __shfl_xor(pr, off, 64);
    if (lane == 0) sc[wv * 5 + j] = pr * 0.08838834764831845f;  // 1/sqrt(128)
  }
  __syncthreads();
  float m = -3.0e38f;
  #pragma unroll
  for (int i = 0; i < 20; ++i) m = fmaxf(m, sc[i]);
  float s = 0.f;
  #pragma unroll
  for (int i = 0; i < 20; ++i) s += expf(sc[i] - m);
  const float inv = 1.0f / s;
  float c0 = 0.f, c1 = 0.f;
  #pragma unroll
  for (int j = 0; j < 5; ++j) {
    const float wk = expf(sc[wv * 5 + j] - m) * inv;
    c0 = fmaf(wk, V[j].x, c0);
    c1 = fmaf(wk, V[j].y, c1);
  }
  ctxp[wv][2 * lane] = c0;
  ctxp[wv][2 * lane + 1] = c1;
  __syncthreads();
  if (t < 128)
    out[b * 128 + t] = (ctxp[0][t] + ctxp[1][t]) + (ctxp[2][t] + ctxp[3][t]);
}

extern "C" void kernel_launch(void* const* d_in, const int* in_sizes, int n_in,
                              void* d_out, int out_size, void* d_ws, size_t ws_size,
                              hipStream_t stream) {
  (void)in_sizes; (void)n_in; (void)out_size; (void)ws_size;
  const float* pe = (const float*)d_in[0];
  const float* ge = (const float*)d_in[1];
  const float* Wq = (const float*)d_in[2];
  const float* bq = (const float*)d_in[3];
  const float* Wk = (const float*)d_in[4];
  const float* bk = (const float*)d_in[5];
  const float* Wv = (const float*)d_in[6];
  const float* bvp = (const float*)d_in[7];
  const float* W1 = (const float*)d_in[8];
  const float* b1 = (const float*)d_in[9];
  const float* w2 = (const float*)d_in[10];
  // d_in[11] = b2: uniform over n -> cancels in argmax; absent from output path.

  char* w = (char*)d_ws;
  float* Wf32 = (float*)w;                               // 131072 B
  double* qbT = (double*)(w + 131072);                   // 65536 B
  float* Qm = (float*)(w + 196608);                      // 32768 B
  unsigned long long* cells =
      (unsigned long long*)(w + 229376);                 // 10240 B
  double2* c12 = (double2*)(w + 239616);                 // 2048 B
  double* simd = (double*)(w + 241664);                  // 10,240,000 B
  float* sim2f = (float*)(w + 10481664);                 // 5,120,000 B (~15.6 MB total)
  float* out = (float*)d_out;

  kprep<<<dim3(321), dim3(128), 0, stream>>>(pe, Wq, bq, Wk, bk, W1, b1, w2,
                                             Wf32, qbT, Qm, cells, c12);
  kfused<<<dim3(1250), dim3(256), 0, stream>>>(ge, Wf32, qbT, c12, simd, sim2f);
  ksel2<<<dim3(1976), dim3(256), 0, stream>>>(simd, sim2f, cells);
  kfinal<<<dim3(64), dim3(256), 0, stream>>>(ge, Wv, bvp, Qm, cells, out);
}

// Round 13
// 265.971 us; speedup vs baseline: 1.5024x; 1.0876x over previous
//
#include <hip/hip_runtime.h>

#define NG 20000

// ---------- JAX threefry2x32, key = (0, 42) ----------
__device__ __forceinline__ void threefry2x32(unsigned x0, unsigned x1,
                                             unsigned& o0, unsigned& o1) {
  const unsigned ks0 = 0u;
  const unsigned ks1 = 42u;
  const unsigned ks2 = 0x1BD11BDAu ^ 0u ^ 42u;
  x0 += ks0; x1 += ks1;
#define TFR(r) { x0 += x1; x1 = (x1 << (r)) | (x1 >> (32 - (r))); x1 ^= x0; }
  TFR(13) TFR(15) TFR(26) TFR(6)
  x0 += ks1; x1 += ks2 + 1u;
  TFR(17) TFR(29) TFR(16) TFR(24)
  x0 += ks2; x1 += ks0 + 2u;
  TFR(13) TFR(15) TFR(26) TFR(6)
  x0 += ks0; x1 += ks1 + 3u;
  TFR(17) TFR(29) TFR(16) TFR(24)
  x0 += ks1; x1 += ks2 + 4u;
  TFR(13) TFR(15) TFR(26) TFR(6)
  x0 += ks2; x1 += ks0 + 5u;
#undef TFR
  o0 = x0; o1 = x1;
}

// JAX threefry_partitionable: bits(i) = o0 ^ o1 of threefry((0,42),(0,i))
__device__ __forceinline__ unsigned tfbits(unsigned ctr) {
  unsigned o0, o1;
  threefry2x32(0u, ctr, o0, o1);
  return o0 ^ o1;
}

// fp32 fast-screen gumbel, constant-folded: g = -ln2*log2(-log2(u)) - ln(ln2)
__device__ __forceinline__ float gumbel32(unsigned bits) {
  float f = __uint_as_float((bits >> 9) | 0x3f800000u) - 1.0f;
  float u = fmaxf(f, 1.17549435e-38f);
  const float l2u = __log2f(u);                     // strictly < 0
  return fmaf(-0.69314718056f, __log2f(-l2u), 0.3665129206f);
}

// exact fp64 gumbel; u is a 23-bit dyadic rational, exact in double
__device__ __forceinline__ double gumbel64(unsigned bits) {
  float f = __uint_as_float((bits >> 9) | 0x3f800000u) - 1.0f;
  double u = (double)fmaxf(f, 1.17549435e-38f);
  return -log(-log(u));
}

// pack fp64 score (top 49 monotone bits) + 15-bit (32767-n): u64 max == (score, then smaller n)
__device__ __forceinline__ unsigned long long packcell(double v, int n) {
  unsigned long long u = (unsigned long long)__double_as_longlong(v);
  u = (u >> 63) ? ~u : (u | 0x8000000000000000ull);
  return (u & 0xFFFFFFFFFFFF8000ull) | (unsigned long long)(32767 - n);
}

// ---------- prep: Wf=Wk@W1k (fp64 math, fp32 store), Q, qbT; c12; zero cells ----------
__global__ __launch_bounds__(128) void kprep(
    const float* __restrict__ pe, const float* __restrict__ Wq,
    const float* __restrict__ bq, const float* __restrict__ Wk,
    const float* __restrict__ bk, const float* __restrict__ W1,
    const float* __restrict__ b1, const float* __restrict__ w2,
    float* __restrict__ Wf32, double* __restrict__ qbT,
    float* __restrict__ Qm, unsigned long long* __restrict__ cells,
    double2* __restrict__ c12) {
  __shared__ float L[512];
  __shared__ double Ld[128];
  const int t = threadIdx.x;
  const int bid = blockIdx.x;
  if (bid < 256) {
    L[t] = Wk[bid * 128 + t];
    __syncthreads();
    double acc = 0.0;
    #pragma unroll 16
    for (int j = 0; j < 128; ++j)
      acc = fma((double)L[j], (double)W1[(128 + j) * 128 + t], acc);
    Wf32[bid * 128 + t] = (float)acc;
  } else if (bid < 320) {
    const int b = bid - 256;
    #pragma unroll
    for (int i = 0; i < 4; ++i) L[t + 128 * i] = pe[b * 512 + t + 128 * i];
    __syncthreads();
    double q = (double)bq[t];
    #pragma unroll 16
    for (int f = 0; f < 512; ++f)
      q = fma((double)L[f], (double)Wq[f * 128 + t], q);
    Qm[b * 128 + t] = (float)q;   // epilogue path stays fp32
    Ld[t] = q;
    __syncthreads();
    // qb[b,d=t] = Q@W1[:128] + b1 + bk@W1[128:]; store transposed qbT[d][b]
    double acc = (double)b1[t];
    #pragma unroll 8
    for (int j = 0; j < 128; ++j) {
      acc = fma(Ld[j], (double)W1[j * 128 + t], acc);
      acc = fma((double)bk[j], (double)W1[(128 + j) * 128 + t], acc);
    }
    qbT[t * 64 + b] = acc;
  } else {
    for (int i = t; i < 1280; i += 128) cells[i] = 0ull;
    const double w2d = (double)w2[t];
    c12[t] = make_double2(0.55 * w2d, 0.45 * w2d);
  }
}

// ---------- fully fused: kp(fp32 GEMM) + sim(fp64) + screen + exact + atomic ----------
// block = 256 threads, 16 genes (1250 blocks, 20000 = 1250*16 exact).
// Phase 1: wave wv owns genes wv*4..wv*4+3; thread owns d = lane, lane+64; ge tile
//   in LDS (broadcast ds_read_b128), Wf32 depth-2 register stream. fp32 fmaf,
//   per-acc f ascending -> kp bit-identical to R12.
// Phase 2: kp -> kpL; wave wv computes fp64 sim for genes {wv,wv+4,wv+8,wv+12},
//   lane = batch; stores (float)(2*sim) to simLf[b][g].
// Phase 3: thread handles 5 cells (cell = i*256+t = b*20+k); per cell: fp32 top-2
//   screen over the block's 16 genes (idx = cell*20000 + n), fp64-exact winner
//   (+ runner-up iff gap < 1e-4), one atomicMax per cell. Max-of-window-maxima
//   with exact window winners == global exact argmax (same guarantee as R12).
__global__ __launch_bounds__(256) void kfused(
    const float* __restrict__ ge, const float* __restrict__ Wf32,
    const double* __restrict__ qbT, const double2* __restrict__ c12,
    unsigned long long* __restrict__ cells) {
  __shared__ double SBd[2048];   // phase1: geL (16 KB as float); phase2/3: simLf
  __shared__ float kpL[2048];    // kp[16][128]
  float* geL = (float*)SBd;
  float* simLf = (float*)SBd;    // [64][17]
  const int t = threadIdx.x;
  const int wv = t >> 6;
  const int lane = t & 63;
  const int g0 = blockIdx.x * 16;     // 1250 blocks * 16 genes

  // stage ge tile (16 genes x 256 f) -> LDS: 4 independent float4 per thread
  {
    const float4* src = (const float4*)(ge + (size_t)g0 * 256);
    float4* dst = (float4*)geL;
    #pragma unroll
    for (int i = 0; i < 4; ++i) dst[t + i * 256] = src[t + i * 256];
  }
  __syncthreads();

  // ---- phase 1: fp32 GEMM from LDS genes + streamed Wf32 ----
  float acc[4][2];
  #pragma unroll
  for (int j = 0; j < 4; ++j) { acc[j][0] = 0.f; acc[j][1] = 0.f; }
  const float* wb0 = Wf32 + lane;
  const float* wb1 = Wf32 + lane + 64;
  const float* gL = geL + wv * 4 * 256;

  float wc0[4], wc1[4];
  #pragma unroll
  for (int ff = 0; ff < 4; ++ff) {
    wc0[ff] = wb0[ff * 128];
    wc1[ff] = wb1[ff * 128];
  }
  for (int f0 = 0; f0 < 256; f0 += 4) {
    float wn0[4], wn1[4];
    if (f0 < 252) {
      #pragma unroll
      for (int ff = 0; ff < 4; ++ff) {
        wn0[ff] = wb0[(f0 + 4 + ff) * 128];
        wn1[ff] = wb1[(f0 + 4 + ff) * 128];
      }
    }
    #pragma unroll
    for (int j = 0; j < 4; ++j) {
      const float4 gv = *(const float4*)(gL + j * 256 + f0);  // ds_read_b128 bcast
      acc[j][0] = fmaf(gv.x, wc0[0], acc[j][0]);
      acc[j][1] = fmaf(gv.x, wc1[0], acc[j][1]);
      acc[j][0] = fmaf(gv.y, wc0[1], acc[j][0]);
      acc[j][1] = fmaf(gv.y, wc1[1], acc[j][1]);
      acc[j][0] = fmaf(gv.z, wc0[2], acc[j][0]);
      acc[j][1] = fmaf(gv.z, wc1[2], acc[j][1]);
      acc[j][0] = fmaf(gv.w, wc0[3], acc[j][0]);
      acc[j][1] = fmaf(gv.w, wc1[3], acc[j][1]);
    }
    #pragma unroll
    for (int ff = 0; ff < 4; ++ff) { wc0[ff] = wn0[ff]; wc1[ff] = wn1[ff]; }
  }

  __syncthreads();   // geL reads done (SBd about to be reused as simLf)
  #pragma unroll
  for (int j = 0; j < 4; ++j) {
    kpL[(wv * 4 + j) * 128 + lane] = acc[j][0];
    kpL[(wv * 4 + j) * 128 + lane + 64] = acc[j][1];
  }
  __syncthreads();

  // ---- phase 2: fp64 sim (4 genes/wave, lane = batch) ----
  double s[4];
  #pragma unroll
  for (int j = 0; j < 4; ++j) s[j] = 0.0;
  for (int dd = 0; dd < 128; ++dd) {
    const double2 cc = c12[dd];                   // uniform -> s_load
    const double qv = qbT[dd * 64 + lane];        // coalesced, L1-hot
    #pragma unroll
    for (int j = 0; j < 4; ++j) {
      const double kv = (double)kpL[(wv + j * 4) * 128 + dd];  // broadcast
      const double tt = qv + kv;
      s[j] = fma(tt, cc.x, s[j]);
      s[j] = fma(fabs(tt), cc.y, s[j]);
    }
  }
  #pragma unroll
  for (int j = 0; j < 4; ++j)
    simLf[lane * 17 + (wv + j * 4)] = (float)(2.0 * s[j]);
  __syncthreads();

  // ---- phase 3: per-cell screen over this block's 16 genes ----
  #pragma unroll
  for (int i = 0; i < 5; ++i) {
    const int cell = i * 256 + t;                 // = b*20 + k, 0..1279
    const int b = (unsigned)cell / 20u;
    const float* sb = simLf + b * 17;
    float m1 = -3e38f, m2 = -3e38f;
    int n1 = -1, n2 = -1;
    unsigned c1 = 0, c2 = 0;
    const unsigned ib = (unsigned)cell * 20000u + (unsigned)g0;
    #pragma unroll 4
    for (int g = 0; g < 16; ++g) {
      const unsigned bb = tfbits(ib + (unsigned)g);
      const float sc = sb[g] + gumbel32(bb);
      if (sc > m1) { m2 = m1; n2 = n1; c2 = c1; m1 = sc; n1 = g; c1 = bb; }
      else if (sc > m2) { m2 = sc; n2 = g; c2 = bb; }
    }
    unsigned long long pb =
        packcell((double)sb[n1] + gumbel64(c1), g0 + n1);
    if (n2 >= 0 && (m1 - m2) < 1e-4f) {           // screen err 2e-5 << margin
      const unsigned long long u2 =
          packcell((double)sb[n2] + gumbel64(c2), g0 + n2);
      if (u2 > pb) pb = u2;
    }
    atomicMax(&cells[cell], pb);
  }
}

// ---------- epilogue (fp32): 5 interleaved V-GEMVs per wave, softmax over K, context ----------
__global__ __launch_bounds__(256) void kfinal(
    const float* __restrict__ ge, const float* __restrict__ Wv,
    const float* __restrict__ bv, const float* __restrict__ Qm,
    const unsigned long long* __restrict__ cells, float* __restrict__ out) {
  const int b = blockIdx.x;
  const int t = threadIdx.x;
  const int wv = t >> 6;
  const int lane = t & 63;
  __shared__ float sc[20];
  __shared__ float ctxp[4][128];
  const float2 qv = ((const float2*)(Qm + b * 128))[lane];
  const float2 bvv = ((const float2*)bv)[lane];
  const float* gr[5];
  float2 V[5];
  #pragma unroll
  for (int j = 0; j < 5; ++j) {
    const unsigned long long cell = cells[b * 20 + wv * 5 + j];
    const int n = 32767 - (int)(cell & 0x7FFFull);
    gr[j] = ge + (size_t)n * 256;
    V[j] = bvv;
  }
  for (int f = 0; f < 256; f += 4) {
    const float2 w0 = ((const float2*)(Wv + (size_t)(f + 0) * 128))[lane];
    const float2 w1 = ((const float2*)(Wv + (size_t)(f + 1) * 128))[lane];
    const float2 w2_ = ((const float2*)(Wv + (size_t)(f + 2) * 128))[lane];
    const float2 w3 = ((const float2*)(Wv + (size_t)(f + 3) * 128))[lane];
    #pragma unroll
    for (int j = 0; j < 5; ++j) {
      const float4 gv = *(const float4*)(gr[j] + f);   // uniform -> s_load
      V[j].x = fmaf(gv.x, w0.x, V[j].x); V[j].y = fmaf(gv.x, w0.y, V[j].y);
      V[j].x = fmaf(gv.y, w1.x, V[j].x); V[j].y = fmaf(gv.y, w1.y, V[j].y);
      V[j].x = fmaf(gv.z, w2_.x, V[j].x); V[j].y = fmaf(gv.z, w2_.y, V[j].y);
      V[j].x = fmaf(gv.w, w3.x, V[j].x); V[j].y = fmaf(gv.w, w3.y, V[j].y);
    }
  }
  #pragma unroll
  for (int j = 0; j < 5; ++j) {
    float pr = qv.x * V[j].x + qv.y * V[j].y;
    #pragma unroll
    for (int off = 32; off; off >>= 1) pr += __shfl_xor(pr, off, 64);
    if (lane == 0) sc[wv * 5 + j] = pr * 0.08838834764831845f;  // 1/sqrt(128)
  }
  __syncthreads();
  float m = -3.0e38f;
  #pragma unroll
  for (int i = 0; i < 20; ++i) m = fmaxf(m, sc[i]);
  float s = 0.f;
  #pragma unroll
  for (int i = 0; i < 20; ++i) s += expf(sc[i] - m);
  const float inv = 1.0f / s;
  float c0 = 0.f, c1 = 0.f;
  #pragma unroll
  for (int j = 0; j < 5; ++j) {
    const float wk = expf(sc[wv * 5 + j] - m) * inv;
    c0 = fmaf(wk, V[j].x, c0);
    c1 = fmaf(wk, V[j].y, c1);
  }
  ctxp[wv][2 * lane] = c0;
  ctxp[wv][2 * lane + 1] = c1;
  __syncthreads();
  if (t < 128)
    out[b * 128 + t] = (ctxp[0][t] + ctxp[1][t]) + (ctxp[2][t] + ctxp[3][t]);
}

extern "C" void kernel_launch(void* const* d_in, const int* in_sizes, int n_in,
                              void* d_out, int out_size, void* d_ws, size_t ws_size,
                              hipStream_t stream) {
  (void)in_sizes; (void)n_in; (void)out_size; (void)ws_size;
  const float* pe = (const float*)d_in[0];
  const float* ge = (const float*)d_in[1];
  const float* Wq = (const float*)d_in[2];
  const float* bq = (const float*)d_in[3];
  const float* Wk = (const float*)d_in[4];
  const float* bk = (const float*)d_in[5];
  const float* Wv = (const float*)d_in[6];
  const float* bvp = (const float*)d_in[7];
  const float* W1 = (const float*)d_in[8];
  const float* b1 = (const float*)d_in[9];
  const float* w2 = (const float*)d_in[10];
  // d_in[11] = b2: uniform over n -> cancels in argmax; absent from output path.

  char* w = (char*)d_ws;
  float* Wf32 = (float*)w;                               // 131072 B
  double* qbT = (double*)(w + 131072);                   // 65536 B
  float* Qm = (float*)(w + 196608);                      // 32768 B
  unsigned long long* cells =
      (unsigned long long*)(w + 229376);                 // 10240 B
  double2* c12 = (double2*)(w + 239616);                 // 2048 B (~0.24 MB total)
  float* out = (float*)d_out;

  kprep<<<dim3(321), dim3(128), 0, stream>>>(pe, Wq, bq, Wk, bk, W1, b1, w2,
                                             Wf32, qbT, Qm, cells, c12);
  kfused<<<dim3(1250), dim3(256), 0, stream>>>(ge, Wf32, qbT, c12, cells);
  kfinal<<<dim3(64), dim3(256), 0, stream>>>(ge, Wv, bvp, Qm, cells, out);
}